// Round 1
// baseline (3628.657 us; speedup 1.0000x reference)
//
#include <hip/hip_runtime.h>
#include <hip/hip_bf16.h>

// Problem constants (reference: N=4096, V=50000, D=64, EPS=1e-7)
#define NROWS 4096
#define VOCAB 50000
#define DIM   64
#define EPS   1e-7f

constexpr int BM  = 32;     // rows per block (K1)
constexpr int BV  = 128;    // vocab cols per tile (K1)
constexpr int TPB = 256;
constexpr int VS  = 4;      // vocab chunks (grid.y of K1)
constexpr int NTILES = (VOCAB + BV - 1) / BV;            // 391
constexpr int TPC    = (NTILES + VS - 1) / VS;           // 98 tiles/chunk

// ---------------------------------------------------------------------------
// K1: logits = inputs @ emb^T, written to out (used as scratch), plus
// per-(chunk,row) online-softmax partials (m, z).
// Grid: (NROWS/BM, VS). Block: 256.
// ---------------------------------------------------------------------------
__global__ __launch_bounds__(TPB) void k1_logits_stats(
    const float* __restrict__ inp, const float* __restrict__ emb,
    float* __restrict__ out, float* __restrict__ mpart, float* __restrict__ zpart)
{
    __shared__ float a_s[BM][DIM];       // 8 KB
    __shared__ float e_s[BV][DIM + 4];   // 34 KB, +4 pad to break bank stride

    const int rbase = blockIdx.x * BM;
    const int chunk = blockIdx.y;
    const int tid = threadIdx.x;
    const int tx = tid & 31;    // 32 v-lanes
    const int ty = tid >> 5;    // 8 row groups of 4

    // Load A tile (32x64 floats = 512 float4, 2 per thread), coalesced.
    {
        const float4* g = (const float4*)(inp + (size_t)rbase * DIM);
        for (int i = tid; i < BM * DIM / 4; i += TPB) {
            int r = i >> 4, c = i & 15;
            ((float4*)&a_s[r][0])[c] = g[i];
        }
    }

    float m_t[4], z_t[4];
#pragma unroll
    for (int i = 0; i < 4; ++i) { m_t[i] = -1e30f; z_t[i] = 0.f; }

    int t0 = chunk * TPC;
    int t1 = t0 + TPC; if (t1 > NTILES) t1 = NTILES;

    for (int t = t0; t < t1; ++t) {
        const int v0 = t * BV;
        __syncthreads();   // protect a_s (first iter) / e_s (reuse)
        // Load E tile: 128 rows x 16 float4 = 2048 float4, 8 per thread.
        for (int i = tid; i < BV * DIM / 4; i += TPB) {
            int vv = i >> 4, c = i & 15;
            int v = v0 + vv;
            float4 val = make_float4(0.f, 0.f, 0.f, 0.f);
            if (v < VOCAB) val = ((const float4*)(emb + (size_t)v * DIM))[c];
            ((float4*)&e_s[vv][0])[c] = val;
        }
        __syncthreads();

        float acc[4][4];
#pragma unroll
        for (int i = 0; i < 4; ++i)
#pragma unroll
            for (int j = 0; j < 4; ++j) acc[i][j] = 0.f;

#pragma unroll
        for (int d = 0; d < DIM; d += 4) {
            float4 a4[4], e4[4];
#pragma unroll
            for (int i = 0; i < 4; ++i) a4[i] = *(const float4*)&a_s[ty * 4 + i][d];
#pragma unroll
            for (int j = 0; j < 4; ++j) e4[j] = *(const float4*)&e_s[j * 32 + tx][d];
#pragma unroll
            for (int i = 0; i < 4; ++i)
#pragma unroll
                for (int j = 0; j < 4; ++j) {
                    acc[i][j] = fmaf(a4[i].x, e4[j].x, acc[i][j]);
                    acc[i][j] = fmaf(a4[i].y, e4[j].y, acc[i][j]);
                    acc[i][j] = fmaf(a4[i].z, e4[j].z, acc[i][j]);
                    acc[i][j] = fmaf(a4[i].w, e4[j].w, acc[i][j]);
                }
        }

        // Store logits + per-thread online (m,z) update.
#pragma unroll
        for (int i = 0; i < 4; ++i) {
            const int r = rbase + ty * 4 + i;
#pragma unroll
            for (int j = 0; j < 4; ++j) {
                const int v = v0 + j * 32 + tx;
                if (v < VOCAB) {
                    const float x = acc[i][j];
                    out[(size_t)r * VOCAB + v] = x;
                    if (x <= m_t[i]) {
                        z_t[i] += __expf(x - m_t[i]);
                    } else {
                        z_t[i] = z_t[i] * __expf(m_t[i] - x) + 1.f;
                        m_t[i] = x;
                    }
                }
            }
        }
    }

    // Reduce (m,z) across the 32 tx lanes (they live in one half-wave).
#pragma unroll
    for (int i = 0; i < 4; ++i) {
        float m = m_t[i], z = z_t[i];
        for (int off = 16; off; off >>= 1) {
            float mo = __shfl_xor(m, off);
            float zo = __shfl_xor(z, off);
            float mn = fmaxf(m, mo);
            z = z * __expf(m - mn) + zo * __expf(mo - mn);
            m = mn;
        }
        if (tx == 0) {
            const int r = rbase + ty * 4 + i;
            mpart[chunk * NROWS + r] = m;
            zpart[chunk * NROWS + r] = z;
        }
    }
}

// ---------------------------------------------------------------------------
// K2: merge per-chunk partials -> per-row max m and 1/Z.
// ---------------------------------------------------------------------------
__global__ __launch_bounds__(TPB) void k2_merge(
    const float* __restrict__ mpart, const float* __restrict__ zpart,
    float* __restrict__ mrow, float* __restrict__ zinv)
{
    const int n = blockIdx.x * blockDim.x + threadIdx.x;
    if (n >= NROWS) return;
    float m = -1e30f;
    for (int c = 0; c < VS; ++c) m = fmaxf(m, mpart[c * NROWS + n]);
    float z = 0.f;
    for (int c = 0; c < VS; ++c) z += zpart[c * NROWS + n] * __expf(mpart[c * NROWS + n] - m);
    mrow[n] = m;
    zinv[n] = 1.f / z;
}

// ---------------------------------------------------------------------------
// K3: in-place logits -> probs; accumulate clipped row sum S_n.
// Grid: NROWS blocks; one block per row.
// ---------------------------------------------------------------------------
__global__ __launch_bounds__(TPB) void k3_probs(
    float* __restrict__ out, const float* __restrict__ mrow,
    const float* __restrict__ zinv, float* __restrict__ S)
{
    const int n = blockIdx.x;
    const float m = mrow[n];
    const float iz = zinv[n];
    const float hi = 1.0f - EPS;
    float4* p = (float4*)(out + (size_t)n * VOCAB);
    float s = 0.f;
    const int NF4 = VOCAB / 4;  // 12500
    for (int i = threadIdx.x; i < NF4; i += TPB) {
        float4 l = p[i];
        float4 q;
        q.x = __expf(l.x - m) * iz;
        q.y = __expf(l.y - m) * iz;
        q.z = __expf(l.z - m) * iz;
        q.w = __expf(l.w - m) * iz;
        p[i] = q;
        s += fminf(fmaxf(q.x, EPS), hi);
        s += fminf(fmaxf(q.y, EPS), hi);
        s += fminf(fmaxf(q.z, EPS), hi);
        s += fminf(fmaxf(q.w, EPS), hi);
    }
    // block reduce s
    for (int off = 32; off; off >>= 1) s += __shfl_down(s, off);
    __shared__ float red[4];
    const int wid = threadIdx.x >> 6;
    if ((threadIdx.x & 63) == 0) red[wid] = s;
    __syncthreads();
    if (threadIdx.x == 0) {
        float tot = red[0] + red[1] + red[2] + red[3];
        S[n] = tot;
    }
}

// ---------------------------------------------------------------------------
// K4: loss = mean_n( log(S_n) - log(clip(p[n, label[n]])) ) -> out[N*V]
// ---------------------------------------------------------------------------
__global__ __launch_bounds__(TPB) void k4_loss(
    const float* __restrict__ out_probs, const int* __restrict__ label,
    const float* __restrict__ S, float* __restrict__ lossOut)
{
    const float hi = 1.0f - EPS;
    float acc = 0.f;
    for (int n = threadIdx.x; n < NROWS; n += TPB) {
        const int lab = label[n];
        float pl = out_probs[(size_t)n * VOCAB + lab];
        pl = fminf(fmaxf(pl, EPS), hi);
        acc += logf(S[n]) - logf(pl);
    }
    for (int off = 32; off; off >>= 1) acc += __shfl_down(acc, off);
    __shared__ float red[4];
    const int wid = threadIdx.x >> 6;
    if ((threadIdx.x & 63) == 0) red[wid] = acc;
    __syncthreads();
    if (threadIdx.x == 0) {
        float tot = red[0] + red[1] + red[2] + red[3];
        lossOut[0] = tot / (float)NROWS;
    }
}

extern "C" void kernel_launch(void* const* d_in, const int* in_sizes, int n_in,
                              void* d_out, int out_size, void* d_ws, size_t ws_size,
                              hipStream_t stream)
{
    const int*   label = (const int*)d_in[0];
    const float* inp   = (const float*)d_in[1];   // [4096, 64]
    const float* emb   = (const float*)d_in[2];   // [50000, 64]
    float* out = (float*)d_out;                   // [4096*50000] probs + [1] loss

    // Workspace layout (floats): mpart[VS*N], zpart[VS*N], mrow[N], zinv[N], S[N]
    float* w     = (float*)d_ws;
    float* mpart = w;
    float* zpart = w + (size_t)VS * NROWS;
    float* mrow  = w + (size_t)2 * VS * NROWS;
    float* zinv  = mrow + NROWS;
    float* S     = zinv + NROWS;

    dim3 g1(NROWS / BM, VS);
    k1_logits_stats<<<g1, TPB, 0, stream>>>(inp, emb, out, mpart, zpart);
    k2_merge<<<(NROWS + TPB - 1) / TPB, TPB, 0, stream>>>(mpart, zpart, mrow, zinv);
    k3_probs<<<NROWS, TPB, 0, stream>>>(out, mrow, zinv, S);
    k4_loss<<<1, TPB, 0, stream>>>(out, label, S, out + (size_t)NROWS * VOCAB);
}